// Round 13
// baseline (2584.951 us; speedup 1.0000x reference)
//
#include <hip/hip_runtime.h>
#include <stdint.h>

#define T_STEPS 512
#define B_ALL   512
#define SDIM    64
#define HID     128
#define ADIM    10
#define CB      16      // batch rows per chunk (one full MFMA row-tile)
#define NCH     32      // chunks
#define LROW    17      // transposed h-LDS pad (u32 words per unit row)
#define WPAD    133     // Wout LDS row pad (133 % 32 = 5: spreads banks ~2-way)

typedef __attribute__((ext_vector_type(4))) float f32x4;
typedef __attribute__((ext_vector_type(8))) short s16x8;

#define MFMA(a,b,c) __builtin_amdgcn_mfma_f32_16x16x32_bf16(a,b,c,0,0,0)
#define SC_AGENT __HIP_MEMORY_SCOPE_AGENT

__device__ __forceinline__ unsigned short bf_rne(float f){
    union{float f; unsigned int u;} v; v.f = f;
    unsigned int r = v.u + 0x7fffu + ((v.u >> 16) & 1u);
    return (unsigned short)(r >> 16);
}
__device__ __forceinline__ float us_to_f(unsigned short h){
    union{unsigned int u; float f;} v; v.u = ((unsigned int)h) << 16; return v.f;
}
__device__ __forceinline__ void split_pair(float f, unsigned short& hi, unsigned short& lo){
    hi = bf_rne(f);
    lo = bf_rne(f - us_to_f(hi));
}
__device__ __forceinline__ void load_split8(const float* p, s16x8& h, s16x8& l){
#pragma unroll
    for (int i = 0; i < 8; i++){
        unsigned short a, b; split_pair(p[i], a, b);
        h[i] = (short)a; l[i] = (short)b;
    }
}
__device__ __forceinline__ float sigm(float x){ return 1.f / (1.f + __expf(-x)); }
__device__ __forceinline__ float tanh_f(float x){ return 1.f - 2.f / (__expf(2.f * x) + 1.f); }

// ---- 3-stage K-split pipeline (one CU per role per chunk) ----
//   R0: x(t)@Wih0^T + h0(t-1)@Whh0^T -> h0(t); h0 recurrence in LDS; h0 -> hring
//   A : pA(t) = h0(t)@Wih1^T -> aring   (direct full-row ring loads, no staging;
//        one alignment __syncthreads per step makes the progress publish sound)
//   R1: pA + h1(t-1)@Whh1^T -> h1(t);   h1 recurrence in LDS; action in-CU
// Rings self-tagged per word (2-bit epoch, tag=((t>>dsh)+1)&3, 0=never).
// 4B stores atomic -> no torn words, no drains. Backpressure: consumers
// publish "steps < t consumed" at TOP of step t AFTER a WG barrier (so the
// publish certifies ALL waves); producer of slot t waits prog >= t-(D-1).
// Depth D = 8/4/2/1 by ws size (dsh runtime). Slack (D-1) < epoch length (D)
// -> a slot's content is only ever expected-epoch or one epoch stale.
__device__ __forceinline__ uint32_t ep_tag(int t, int dsh){
    return (uint32_t)(((t >> dsh) + 1) & 3);
}
__device__ __forceinline__ void wait_word(const uint32_t* p, uint32_t v, uint32_t& seen){
    if (seen >= v) return;
    uint32_t c;
    while ((c = __hip_atomic_load(p, __ATOMIC_RELAXED, SC_AGENT)) < v)
        __builtin_amdgcn_s_sleep(1);
    seen = c;
    __asm__ volatile("" ::: "memory");
}
// lane's base index into a 32KB fp32 gates slot: [(w*4+lq)*64 + lm*4] (+r)
__device__ __forceinline__ int gidx(int w, int lq, int lm){ return (w * 4 + lq) * 64 + lm * 4; }

__device__ __forceinline__ void ring_load16(const float* slot, int i0, unsigned long long* pw){
#pragma unroll
    for (int g = 0; g < 4; g++){
        const unsigned long long* p = (const unsigned long long*)(slot + g * 2048 + i0);
        pw[g * 2]     = __hip_atomic_load(p,     __ATOMIC_RELAXED, SC_AGENT);
        pw[g * 2 + 1] = __hip_atomic_load(p + 1, __ATOMIC_RELAXED, SC_AGENT);
    }
}
__device__ __forceinline__ uint32_t tags_bad16(const unsigned long long* pw, uint32_t e){
    uint32_t bad = 0;
#pragma unroll
    for (int k = 0; k < 8; k++){
        uint32_t a = (uint32_t)pw[k], b = (uint32_t)(pw[k] >> 32);
        bad |= ((a ^ e) & 3u) | ((b ^ e) & 3u);
    }
    return bad;
}
__device__ __forceinline__ void pub_f4(float* dst, f32x4 v, uint32_t e){
    uint32_t q0 = (__float_as_uint(v[0]) & ~3u) | e;
    uint32_t q1 = (__float_as_uint(v[1]) & ~3u) | e;
    uint32_t q2 = (__float_as_uint(v[2]) & ~3u) | e;
    uint32_t q3 = (__float_as_uint(v[3]) & ~3u) | e;
    __hip_atomic_store((unsigned long long*)dst,
        ((unsigned long long)q1 << 32) | q0, __ATOMIC_RELAXED, SC_AGENT);
    __hip_atomic_store((unsigned long long*)dst + 1,
        ((unsigned long long)q3 << 32) | q2, __ATOMIC_RELAXED, SC_AGENT);
}

__global__ void __launch_bounds__(512, 2)
lstm_pipe3(const float* __restrict__ x,
           const float* __restrict__ Wih0, const float* __restrict__ Whh0,
           const float* __restrict__ bih0, const float* __restrict__ bhh0,
           const float* __restrict__ Wih1, const float* __restrict__ Whh1,
           const float* __restrict__ bih1, const float* __restrict__ bhh1,
           const float* __restrict__ Wout, const float* __restrict__ bout,
           float* __restrict__ out, unsigned char* __restrict__ ws, int dsh)
{
    extern __shared__ uint32_t lds[];
    // R0: hbuf [2][128][LROW] (17408B); R1: hbuf + wlds [16][WPAD]; A: none

    const int tid  = threadIdx.x;
    const int wave = tid >> 6, lane = tid & 63;
    const int lm = lane & 15, lq = lane >> 4;
    const int w  = wave;                       // hidden-block 0..7 (16 units each)

    const int c    = blockIdx.x / 3;
    const int role = blockIdx.x - c * 3;       // 0=R0 1=A 2=R1
    const int b0   = c * CB;

    const int D = 1 << dsh, dmask = D - 1;

    uint32_t* prog = (uint32_t*)(ws + (size_t)c * 512);
    // prog[32]=aprog (hring consumed by A), prog[64]=r1prog (aring consumed by R1)
    unsigned char* rb = ws + 16384;
    float*    aring = (float*)rb + (size_t)c * D * 8192;                       // 32KB slots
    uint32_t* hring = (uint32_t*)(rb + (size_t)NCH * D * 32768) + (size_t)c * D * 2048; // 8KB slots

    if (role == 0){
        // ========== R0: h0(t) = lstm(x(t)@Wih0 + h0(t-1)@Whh0); h0 in LDS ==========
        uint32_t* hbuf = lds;                        // [2][128][LROW]
        for (int i = tid; i < 2 * 128 * LROW; i += 512) hbuf[i] = 0;
        __syncthreads();

        s16x8 xh[4][2], xl[4][2];                    // Wih0 frags (K=64)
#pragma unroll
        for (int g = 0; g < 4; g++)
#pragma unroll
            for (int kt = 0; kt < 2; kt++){
                int j = g * HID + w * 16 + lm;
                load_split8(Wih0 + (size_t)j * SDIM + kt * 32 + lq * 8, xh[g][kt], xl[g][kt]);
            }
        s16x8 wh[4][4], wl[4][4];                    // Whh0 frags (K=128)
#pragma unroll
        for (int g = 0; g < 4; g++)
#pragma unroll
            for (int kt = 0; kt < 4; kt++){
                int j = g * HID + w * 16 + lm;
                load_split8(Whh0 + (size_t)j * HID + kt * 32 + lq * 8, wh[g][kt], wl[g][kt]);
            }
        float bias[4];
#pragma unroll
        for (int g = 0; g < 4; g++){
            int j = g * HID + w * 16 + lm;
            bias[g] = bih0[j] + bhh0[j];
        }
        float cst[4] = {0.f, 0.f, 0.f, 0.f};
        uint32_t seenA = 0;

        for (int t = 0; t < T_STEPS; t++){
            uint32_t e = ep_tag(t, dsh);
            f32x4 acc[4];
#pragma unroll
            for (int g = 0; g < 4; g++)
                acc[g] = (f32x4){bias[g], bias[g], bias[g], bias[g]};
            {   // x part (dependency-free)
                const float* xp = x + ((size_t)t * B_ALL + b0 + lm) * SDIM;
                s16x8 Ah[2], Al[2];
#pragma unroll
                for (int kt = 0; kt < 2; kt++)
#pragma unroll
                    for (int j = 0; j < 8; j++){
                        unsigned short hh, ll; split_pair(xp[kt * 32 + lq * 8 + j], hh, ll);
                        Ah[kt][j] = (short)hh; Al[kt][j] = (short)ll;
                    }
#pragma unroll
                for (int kt = 0; kt < 2; kt++)
#pragma unroll
                    for (int g = 0; g < 4; g++){
                        acc[g] = MFMA(Ah[kt], xh[g][kt], acc[g]);
                        acc[g] = MFMA(Ah[kt], xl[g][kt], acc[g]);
                        acc[g] = MFMA(Al[kt], xh[g][kt], acc[g]);
                    }
            }
            {   // h0(t-1) part from LDS (transposed, dbuf (t&1)^1)
                s16x8 Ah[4], Al[4];
                const uint32_t* hb = hbuf + ((t & 1) ^ 1) * 128 * LROW;
#pragma unroll
                for (int kt = 0; kt < 4; kt++)
#pragma unroll
                    for (int j = 0; j < 8; j++){
                        uint32_t v = hb[(kt * 32 + lq * 8 + j) * LROW + lm];
                        Ah[kt][j] = (short)(v >> 16); Al[kt][j] = (short)(v & 0xffffu);
                    }
#pragma unroll
                for (int kt = 0; kt < 4; kt++)
#pragma unroll
                    for (int g = 0; g < 4; g++){
                        acc[g] = MFMA(Ah[kt], wh[g][kt], acc[g]);
                        acc[g] = MFMA(Ah[kt], wl[g][kt], acc[g]);
                        acc[g] = MFMA(Al[kt], wh[g][kt], acc[g]);
                    }
            }
            if (t >= D) wait_word(prog + 32, (uint32_t)(t - (D - 1)), seenA);   // slot reusable

            uint32_t* lb = hbuf + (t & 1) * 128 * LROW + (w * 16 + lm) * LROW + lq * 4;
            uint32_t* hdst = hring + (size_t)(t & dmask) * 2048;
#pragma unroll
            for (int r = 0; r < 4; r++){
                float zi = acc[0][r], zf = acc[1][r], zg = acc[2][r], zo = acc[3][r];
                float cn = sigm(zf) * cst[r] + sigm(zi) * tanh_f(zg);
                float hn = sigm(zo) * tanh_f(cn);
                cst[r] = cn;
                unsigned short hh, ll; split_pair(hn, hh, ll);
                lb[r] = ((uint32_t)hh << 16) | (uint32_t)ll;
                __hip_atomic_store(hdst + (size_t)(lq * 4 + r) * 128 + w * 16 + lm,
                                   ((uint32_t)hh << 16) | ((uint32_t)(ll & 0xfffcu)) | e,
                                   __ATOMIC_RELAXED, SC_AGENT);
            }
            __syncthreads();
        }
    } else if (role == 1){
        // ========== A: pA(t) = h0(t) @ Wih1^T (direct ring loads) ==========
        s16x8 wh[4][4], wl[4][4];
#pragma unroll
        for (int g = 0; g < 4; g++)
#pragma unroll
            for (int kt = 0; kt < 4; kt++){
                int j = g * HID + w * 16 + lm;
                load_split8(Wih1 + (size_t)j * HID + kt * 32 + lq * 8, wh[g][kt], wl[g][kt]);
            }
        uint32_t seenR1 = 0;
        // each wave loads the FULL h0 row slice it needs: row lm, cols kt*32+lq*8..+7
        const int hbase = lm * 64 + lq * 4;          // ull index; + kt*16 + q
        unsigned long long hw[16];
        auto hload = [&](const uint32_t* slot){
            const unsigned long long* p = (const unsigned long long*)slot + hbase;
#pragma unroll
            for (int kt = 0; kt < 4; kt++)
#pragma unroll
                for (int q = 0; q < 4; q++)
                    hw[kt * 4 + q] = __hip_atomic_load(p + kt * 16 + q, __ATOMIC_RELAXED, SC_AGENT);
        };
        hload(hring);                                // prefetch slot 0
        for (int t = 0; t < T_STEPS; t++){
            // ALIGNMENT BARRIER: all waves finished step t-1 (hring reads + aring
            // writes) before the publish below. Without this, wave skew lets R0
            // overwrite a slot a lagging wave still spins on -> deadlock.
            __syncthreads();
            if (t && w == 0 && lane == 0)
                __hip_atomic_store(prog + 32, (uint32_t)t, __ATOMIC_RELAXED, SC_AGENT);
            uint32_t e = ep_tag(t, dsh);
            const uint32_t* slot = hring + (size_t)(t & dmask) * 2048;
            for (;;){
                uint32_t bad = 0;
#pragma unroll
                for (int k = 0; k < 16; k++){
                    uint32_t a = (uint32_t)hw[k], b = (uint32_t)(hw[k] >> 32);
                    bad |= ((a ^ e) & 3u) | ((b ^ e) & 3u);
                }
                if (__all(bad == 0)) break;
                __builtin_amdgcn_s_sleep(1);
                hload(slot);
            }
            s16x8 Ah[4], Al[4];
#pragma unroll
            for (int kt = 0; kt < 4; kt++)
#pragma unroll
                for (int q = 0; q < 4; q++){
                    uint32_t a = (uint32_t)hw[kt * 4 + q], b = (uint32_t)(hw[kt * 4 + q] >> 32);
                    Ah[kt][2*q]   = (short)(a >> 16); Al[kt][2*q]   = (short)(a & 0xffffu);
                    Ah[kt][2*q+1] = (short)(b >> 16); Al[kt][2*q+1] = (short)(b & 0xffffu);
                }
            if (t < T_STEPS - 1)
                hload(hring + (size_t)((t + 1) & dmask) * 2048);   // prefetch next
            f32x4 acc[4];
#pragma unroll
            for (int g = 0; g < 4; g++) acc[g] = (f32x4){0.f, 0.f, 0.f, 0.f};
#pragma unroll
            for (int kt = 0; kt < 4; kt++)
#pragma unroll
                for (int g = 0; g < 4; g++){
                    acc[g] = MFMA(Ah[kt], wh[g][kt], acc[g]);
                    acc[g] = MFMA(Ah[kt], wl[g][kt], acc[g]);
                    acc[g] = MFMA(Al[kt], wh[g][kt], acc[g]);
                }
            if (t >= D) wait_word(prog + 64, (uint32_t)(t - (D - 1)), seenR1);
            float* slotw = aring + (size_t)(t & dmask) * 8192;
#pragma unroll
            for (int g = 0; g < 4; g++)
                pub_f4(slotw + g * 2048 + gidx(w, lq, lm), acc[g], e);
        }
    } else {
        // ========== R1: h1(t) = lstm(pA(t) + h1(t-1)@Whh1); action in-CU ==========
        uint32_t* hbuf = lds;                        // [2][128][LROW]
        uint32_t* wlds = lds + 2 * 128 * LROW;       // [16][WPAD] packed Wout
        for (int i = tid; i < 2 * 128 * LROW; i += 512) hbuf[i] = 0;
        for (int i = tid; i < 16 * 128; i += 512){
            int rrow = i >> 7, k = i & 127;
            uint32_t pk = 0;
            if (rrow < ADIM){
                unsigned short hh, ll;
                split_pair(Wout[(size_t)rrow * HID + k], hh, ll);
                pk = ((uint32_t)hh << 16) | (uint32_t)ll;
            }
            wlds[rrow * WPAD + k] = pk;
        }
        __syncthreads();

        s16x8 wh[4][4], wl[4][4];
#pragma unroll
        for (int g = 0; g < 4; g++)
#pragma unroll
            for (int kt = 0; kt < 4; kt++){
                int j = g * HID + w * 16 + lm;
                load_split8(Whh1 + (size_t)j * HID + kt * 32 + lq * 8, wh[g][kt], wl[g][kt]);
            }
        float bias[4];
#pragma unroll
        for (int g = 0; g < 4; g++){
            int j = g * HID + w * 16 + lm;
            bias[g] = bih1[j] + bhh1[j];
        }
        float cst[4] = {0.f, 0.f, 0.f, 0.f};
        float ob = (lm < ADIM) ? bout[lm] : 0.f;
        const int i0 = gidx(w, lq, lm);

        unsigned long long pw[8];
        ring_load16(aring, i0, pw);                  // prefetch slot 0

        for (int t = 0; t < T_STEPS; t++){
            if (t && w == 0 && lane == 0)
                __hip_atomic_store(prog + 64, (uint32_t)t, __ATOMIC_RELAXED, SC_AGENT);
            uint32_t e = ep_tag(t, dsh);
            const float* slot = aring + (size_t)(t & dmask) * 8192;
            for (;;){
                if (__all(tags_bad16(pw, e) == 0)) break;
                __builtin_amdgcn_s_sleep(1);
                ring_load16(slot, i0, pw);
            }
            f32x4 acc[4];
#pragma unroll
            for (int g = 0; g < 4; g++){
                acc[g][0] = __uint_as_float((uint32_t)pw[g * 2])             + bias[g];
                acc[g][1] = __uint_as_float((uint32_t)(pw[g * 2] >> 32))     + bias[g];
                acc[g][2] = __uint_as_float((uint32_t)pw[g * 2 + 1])         + bias[g];
                acc[g][3] = __uint_as_float((uint32_t)(pw[g * 2 + 1] >> 32)) + bias[g];
            }
            if (t < T_STEPS - 1)
                ring_load16(aring + (size_t)((t + 1) & dmask) * 8192, i0, pw);

            s16x8 Ah[4], Al[4];
            const uint32_t* hb = hbuf + ((t & 1) ^ 1) * 128 * LROW;
#pragma unroll
            for (int kt = 0; kt < 4; kt++)
#pragma unroll
                for (int j = 0; j < 8; j++){
                    uint32_t v = hb[(kt * 32 + lq * 8 + j) * LROW + lm];
                    Ah[kt][j] = (short)(v >> 16); Al[kt][j] = (short)(v & 0xffffu);
                }

            // action(t-1) = tanh(h1(t-1)@Wout^T + bout); rotates across waves
            if (t > 0 && w == (t & 7)){
                f32x4 oacc = (f32x4){0.f, 0.f, 0.f, 0.f};
#pragma unroll
                for (int kt = 0; kt < 4; kt++){
                    s16x8 oh, ol;
#pragma unroll
                    for (int j = 0; j < 8; j++){
                        uint32_t v = wlds[lm * WPAD + kt * 32 + lq * 8 + j];
                        oh[j] = (short)(v >> 16); ol[j] = (short)(v & 0xffffu);
                    }
                    oacc = MFMA(Ah[kt], oh, oacc);
                    oacc = MFMA(Ah[kt], ol, oacc);
                    oacc = MFMA(Al[kt], oh, oacc);
                }
                if (lm < ADIM){
#pragma unroll
                    for (int r = 0; r < 4; r++)
                        out[((size_t)(t - 1) * B_ALL + b0 + lq * 4 + r) * ADIM + lm] =
                            tanh_f(oacc[r] + ob);
                }
            }

#pragma unroll
            for (int kt = 0; kt < 4; kt++)
#pragma unroll
                for (int g = 0; g < 4; g++){
                    acc[g] = MFMA(Ah[kt], wh[g][kt], acc[g]);
                    acc[g] = MFMA(Ah[kt], wl[g][kt], acc[g]);
                    acc[g] = MFMA(Al[kt], wh[g][kt], acc[g]);
                }

            uint32_t* lb = hbuf + (t & 1) * 128 * LROW + (w * 16 + lm) * LROW + lq * 4;
#pragma unroll
            for (int r = 0; r < 4; r++){
                float zi = acc[0][r], zf = acc[1][r], zg = acc[2][r], zo = acc[3][r];
                float cn = sigm(zf) * cst[r] + sigm(zi) * tanh_f(zg);
                float hn = sigm(zo) * tanh_f(cn);
                cst[r] = cn;
                unsigned short hh, ll; split_pair(hn, hh, ll);
                lb[r] = ((uint32_t)hh << 16) | (uint32_t)ll;
            }
            __syncthreads();
        }
        // epilogue: action(511) from h1(511) in LDS buf 1
        if (w == 0){
            s16x8 Ah[4], Al[4];
            const uint32_t* hb = hbuf + ((T_STEPS - 1) & 1) * 128 * LROW;
#pragma unroll
            for (int kt = 0; kt < 4; kt++)
#pragma unroll
                for (int j = 0; j < 8; j++){
                    uint32_t v = hb[(kt * 32 + lq * 8 + j) * LROW + lm];
                    Ah[kt][j] = (short)(v >> 16); Al[kt][j] = (short)(v & 0xffffu);
                }
            f32x4 oacc = (f32x4){0.f, 0.f, 0.f, 0.f};
#pragma unroll
            for (int kt = 0; kt < 4; kt++){
                s16x8 oh, ol;
#pragma unroll
                for (int j = 0; j < 8; j++){
                    uint32_t v = wlds[lm * WPAD + kt * 32 + lq * 8 + j];
                    oh[j] = (short)(v >> 16); ol[j] = (short)(v & 0xffffu);
                }
                oacc = MFMA(Ah[kt], oh, oacc);
                oacc = MFMA(Ah[kt], ol, oacc);
                oacc = MFMA(Al[kt], oh, oacc);
            }
            if (lm < ADIM){
#pragma unroll
                for (int r = 0; r < 4; r++)
                    out[((size_t)(T_STEPS - 1) * B_ALL + b0 + lq * 4 + r) * ADIM + lm] =
                        tanh_f(oacc[r] + ob);
            }
        }
    }
}

extern "C" void kernel_launch(void* const* d_in, const int* in_sizes, int n_in,
                              void* d_out, int out_size, void* d_ws, size_t ws_size,
                              hipStream_t stream)
{
    (void)in_sizes; (void)n_in; (void)out_size;
    const float* x    = (const float*)d_in[0];
    const float* Wih0 = (const float*)d_in[1];
    const float* Whh0 = (const float*)d_in[2];
    const float* bih0 = (const float*)d_in[3];
    const float* bhh0 = (const float*)d_in[4];
    const float* Wih1 = (const float*)d_in[5];
    const float* Whh1 = (const float*)d_in[6];
    const float* bih1 = (const float*)d_in[7];
    const float* bhh1 = (const float*)d_in[8];
    const float* Wout = (const float*)d_in[9];
    const float* bout = (const float*)d_in[10];

    // ws: [0,16KB) progress words (32 chunks x 512B),
    //     [16KB,...) aring | hring, each NCH * D slots
    auto need = [](int dsh){ size_t D = (size_t)1 << dsh;
                             return (size_t)16384 + (size_t)NCH * D * (32768 + 8192); };
    int dsh = 3;
    while (dsh > 0 && ws_size && ws_size < need(dsh)) dsh--;
    hipMemsetAsync(d_ws, 0, need(dsh), stream);

    const size_t lds_bytes = (2 * 128 * LROW + 16 * WPAD) * sizeof(uint32_t);  // 25936 B
    hipLaunchKernelGGL(lstm_pipe3, dim3(NCH * 3), dim3(512), lds_bytes, stream,
                       x, Wih0, Whh0, bih0, bhh0, Wih1, Whh1, bih1, bhh1, Wout, bout,
                       (float*)d_out, (unsigned char*)d_ws, dsh);
}